// Round 6
// baseline (27247.546 us; speedup 1.0000x reference)
//
#include <hip/hip_runtime.h>
#include <math.h>

#define H   256
#define TT  128
#define BT  8
#define PP  6

typedef float f32x4 __attribute__((ext_vector_type(4)));
typedef short bf16x8 __attribute__((ext_vector_type(8)));

__device__ __forceinline__ float sigf(float x) { return 1.0f / (1.0f + __expf(-x)); }
__device__ __forceinline__ float tanh_fast(float x) {
    float t = __expf(-2.0f * fabsf(x));
    float r = (1.0f - t) / (1.0f + t);
    return copysignf(r, x);
}
__device__ __forceinline__ unsigned short f2bf(float f) {
    union { float f; unsigned u; } a; a.f = f;
    unsigned r = a.u + 0x7FFFu + ((a.u >> 16) & 1u);
    return (unsigned short)(r >> 16);
}
__device__ __forceinline__ float bf2f(unsigned short h) {
    union { unsigned u; float f; } a; a.u = ((unsigned)h) << 16; return a.f;
}
__device__ __forceinline__ bf16x8 as_bf8(uint4 u) {
    union { uint4 a; bf16x8 b; } x; x.a = u; return x.b;
}

#define MFMA(a,b,c) __builtin_amdgcn_mfma_f32_16x16x32_bf16(a,b,c,0,0,0)
#define ACC3(acc, ah, al, bh, bl) do { acc = MFMA(ah,bh,acc); acc = MFMA(ah,bl,acc); acc = MFMA(al,bh,acc); } while(0)

// ================= weight packing into MFMA B-fragment order (VERIFIED R4) ===
// unit = 1KB = 64 lanes x 16B; lane l holds W[t = n*16 + (l&15)][k = c*32 + (l>>4)*8 + j]
//   A  (Uz0,Ur0):        uid = n*32 + c*4 + g*2 + hl            [0,512)
//   B  (Uh0):            uid = 512 + n*16 + c*2 + hl            [512,768)
//   C1 (Wz1,Wr1,Wh1):    uid = 768 + n*48 + c*6 + g*2 + hl      [768,1536)   ld=264
//   C2 (Uz1,Ur1):        uid = 1536 + n*32 + c*4 + g*2 + hl     [1536,2048)
//   D  (Uh1):            uid = 2048 + n*16 + c*2 + hl           [2048,2304)
__global__ void pack_w(const float* __restrict__ Uz0, const float* __restrict__ Ur0, const float* __restrict__ Uh0,
                       const float* __restrict__ Wz1, const float* __restrict__ Wr1, const float* __restrict__ Wh1,
                       const float* __restrict__ Uz1, const float* __restrict__ Ur1, const float* __restrict__ Uh1,
                       unsigned short* __restrict__ wsW)
{
    int idx = blockIdx.x * 256 + threadIdx.x;
    int uid = idx >> 6, l = idx & 63;
    if (uid >= 2304) return;
    const float* src; int ld, n, c, hl;
    if (uid < 512) {
        int rel = uid; n = rel >> 5; c = (rel >> 2) & 7; int g = (rel >> 1) & 1; hl = rel & 1;
        src = g ? Ur0 : Uz0; ld = 256;
    } else if (uid < 768) {
        int rel = uid - 512; n = rel >> 4; c = (rel >> 1) & 7; hl = rel & 1;
        src = Uh0; ld = 256;
    } else if (uid < 1536) {
        int rel = uid - 768; n = rel / 48; int r2 = rel % 48; c = r2 / 6; int g = (r2 >> 1) % 3; hl = r2 & 1;
        src = (g == 0) ? Wz1 : ((g == 1) ? Wr1 : Wh1); ld = 264;
    } else if (uid < 2048) {
        int rel = uid - 1536; n = rel >> 5; c = (rel >> 2) & 7; int g = (rel >> 1) & 1; hl = rel & 1;
        src = g ? Ur1 : Uz1; ld = 256;
    } else {
        int rel = uid - 2048; n = rel >> 4; c = (rel >> 1) & 7; hl = rel & 1;
        src = Uh1; ld = 256;
    }
    int t  = n * 16 + (l & 15);
    int k0 = c * 32 + (l >> 4) * 8;
    union { uint4 q; unsigned short s[8]; } o;
    #pragma unroll
    for (int j = 0; j < 8; ++j) {
        float v = src[t * ld + k0 + j];
        unsigned short hi = f2bf(v);
        o.s[j] = (hl == 0) ? hi : f2bf(v - bf2f(hi));
    }
    *(uint4*)(wsW + (size_t)uid * 512 + l * 8) = o.q;
}

// ============ constants: A0t = emb-part + L0*I0 folded; B1t same; WC ========
__global__ void pack_consts(const float* __restrict__ Wz0, const float* __restrict__ Wr0, const float* __restrict__ Wh0,
                            const float* __restrict__ Vw0, const float* __restrict__ Vb0,
                            const float* __restrict__ lz0, const float* __restrict__ lr0, const float* __restrict__ lh0,
                            const float* __restrict__ Wz1, const float* __restrict__ Wr1, const float* __restrict__ Wh1,
                            const float* __restrict__ Vw1, const float* __restrict__ Vb1,
                            const float* __restrict__ lz1, const float* __restrict__ lr1, const float* __restrict__ lh1,
                            const float* __restrict__ emb, float* __restrict__ cst)
{
    int t = threadIdx.x;
    float* A0t = cst; float* B1t = cst + 2304; float* WC = cst + 4608;
    const float* W0s[3] = {Wz0, Wr0, Wh0};
    const float* W1s[3] = {Wz1, Wr1, Wh1};
    const float* ls0[3] = {lz0, lr0, lh0};
    const float* ls1[3] = {lz1, lr1, lh1};
    for (int g = 0; g < 3; ++g) {
        WC[g * H + t] = W0s[g][t * 9];
        float L0g = 0.05f + 0.45f * sigf(ls0[g][t]);
        float L1g = 0.05f + 0.45f * sigf(ls1[g][t]);
        for (int c = 0; c < 3; ++c) {
            float s0 = 0.f, s1 = 0.f, i0 = Vb0[t], i1 = Vb1[t];
            for (int e = 0; e < 8; ++e) {
                float em = emb[c * 8 + e];
                s0 += W0s[g][t * 9 + 1 + e]     * em;
                s1 += W1s[g][t * 264 + 256 + e] * em;
                i0 += Vw0[t * 8 + e] * em;
                i1 += Vw1[t * 8 + e] * em;
            }
            A0t[(g * 3 + c) * H + t] = s0 + L0g * i0;
            B1t[(g * 3 + c) * H + t] = s1 + L1g * i1;
        }
    }
}

// ======== staging macros: all indices compile-time; over-reads land in-buffer
#define FRAG(BUF, C_, SH, SL) do { \
    int hx_ = ((row << 8) + (((C_) & 7) << 5) + (kq << 3)) ^ ((row & 7) << 3); \
    fh[BUF] = as_bf8(*(const uint4*)&SH[hx_]); \
    fl[BUF] = as_bf8(*(const uint4*)&SL[hx_]); } while (0)

#define STG2(BUF, C_, SH, SL, UB, TS, CS) do { \
    FRAG(BUF, C_, SH, SL); \
    _Pragma("unroll") \
    for (int i_ = 0; i_ < 4; ++i_) { \
        const unsigned short* p_ = wsW + ((unsigned)((UB) + (w * 4 + i_) * (TS) + (C_) * (CS)) << 9) + (l << 3); \
        b0h[BUF][i_] = *(const uint4*)p_;          b0l[BUF][i_] = *(const uint4*)(p_ + 512); \
        b1h[BUF][i_] = *(const uint4*)(p_ + 1024); b1l[BUF][i_] = *(const uint4*)(p_ + 1536); } } while (0)

#define STG1(BUF, C_, SH, SL, UB, TS, CS, OFF) do { \
    FRAG(BUF, C_, SH, SL); \
    _Pragma("unroll") \
    for (int i_ = 0; i_ < 4; ++i_) { \
        const unsigned short* p_ = wsW + ((unsigned)((UB) + (w * 4 + i_) * (TS) + (C_) * (CS)) << 9) + (l << 3) + (OFF); \
        b0h[BUF][i_] = *(const uint4*)p_;          b0l[BUF][i_] = *(const uint4*)(p_ + 512); } } while (0)

// ================= persistent MFMA scan: 256 thr, 4 waves x 4 N-tiles =======
__global__ __launch_bounds__(256) void trs_scan(
    const float* __restrict__ x, const unsigned short* __restrict__ wsW,
    const float* __restrict__ cst, const float* __restrict__ fcw, const float* __restrict__ fcb,
    float* __restrict__ out)
{
    __shared__ __align__(16) unsigned short h0h[4096], h0l[4096];
    __shared__ __align__(16) unsigned short h1h[4096], h1l[4096];
    __shared__ __align__(16) unsigned short rhh[4096], rhl[4096];
    __shared__ float xm[BT][TT];
    __shared__ unsigned char xcl[BT][TT];

    const int tid = threadIdx.x;
    const int w = tid >> 6, l = tid & 63;
    const int r0b = blockIdx.x * BT;
    const int row = l & 15, kq = l >> 4;
    const int lrow = kq * 4;
    const bool epi = (l < 32);

    const float* A0t = cst; const float* B1t = cst + 2304; const float* WC = cst + 4608;

    for (int i = tid; i < 4096; i += 256) {
        h0h[i] = 0; h0l[i] = 0; h1h[i] = 0; h1l[i] = 0; rhh[i] = 0; rhl[i] = 0;
    }
    for (int i = tid; i < BT * TT; i += 256) {
        int b = i >> 7, t2 = i & 127;
        float2 v = *(const float2*)(x + ((size_t)(r0b + b) * TT + t2) * 2);
        xm[b][t2] = v.x;
        int c = (int)v.y; c = c < 0 ? 0 : (c > 2 ? 2 : c);
        xcl[b][t2] = (unsigned char)c;
    }
    __syncthreads();

    int tcol[4];
    #pragma unroll
    for (int i = 0; i < 4; ++i) tcol[i] = (w * 4 + i) * 16 + row;

    const f32x4 fz = {0.f, 0.f, 0.f, 0.f};

    for (int step = 0; step < TT; ++step) {
        float zv[4][4], h0f[4][4], z1v[4][4], h1f[4][4];
        f32x4 awh[4];

        // ================= Phase A: h0 @ {Uz0,Ur0}^T =================
        {
            f32x4 accz[4], accr[4];
            #pragma unroll
            for (int i = 0; i < 4; ++i) { accz[i] = fz; accr[i] = fz; }
            bf16x8 fh[2], fl[2];
            uint4 b0h[2][4], b0l[2][4], b1h[2][4], b1l[2][4];
            STG2(0, 0, h0h, h0l, 0, 32, 4);
            #pragma unroll
            for (int c = 0; c < 8; ++c) {
                if (c & 1) STG2(0, c + 1, h0h, h0l, 0, 32, 4);
                else       STG2(1, c + 1, h0h, h0l, 0, 32, 4);
                const int pb = c & 1;
                #pragma unroll
                for (int i = 0; i < 4; ++i) {
                    ACC3(accz[i], fh[pb], fl[pb], as_bf8(b0h[pb][i]), as_bf8(b0l[pb][i]));
                    ACC3(accr[i], fh[pb], fl[pb], as_bf8(b1h[pb][i]), as_bf8(b1l[pb][i]));
                }
            }
            if (epi) {
                #pragma unroll
                for (int i = 0; i < 4; ++i) {
                    int t = tcol[i];
                    float wc0 = WC[t], wc1 = WC[256 + t];
                    #pragma unroll
                    for (int j = 0; j < 4; ++j) {
                        int r = lrow + j;
                        int cls = xcl[r][step]; float m = xm[r][step];
                        float z  = sigf(accz[i][j] + m * wc0 + A0t[cls * 256 + t]);
                        float rg = sigf(accr[i][j] + m * wc1 + A0t[(3 + cls) * 256 + t]);
                        int hx = (r * 256 + t) ^ ((r & 7) << 3);
                        float hf = bf2f(h0h[hx]) + bf2f(h0l[hx]);
                        float rh = rg * hf;
                        unsigned short hi = f2bf(rh);
                        rhh[hx] = hi; rhl[hx] = f2bf(rh - bf2f(hi));
                        zv[i][j] = z; h0f[i][j] = hf;
                    }
                }
            }
        }
        __syncthreads();

        // ================= Phase B: (r.h0) @ Uh0^T =================
        {
            f32x4 accb[4];
            #pragma unroll
            for (int i = 0; i < 4; ++i) accb[i] = fz;
            bf16x8 fh[2], fl[2];
            uint4 b0h[2][4], b0l[2][4];
            STG1(0, 0, rhh, rhl, 512, 16, 2, 0);
            #pragma unroll
            for (int c = 0; c < 8; ++c) {
                if (c & 1) STG1(0, c + 1, rhh, rhl, 512, 16, 2, 0);
                else       STG1(1, c + 1, rhh, rhl, 512, 16, 2, 0);
                const int pb = c & 1;
                #pragma unroll
                for (int i = 0; i < 4; ++i)
                    ACC3(accb[i], fh[pb], fl[pb], as_bf8(b0h[pb][i]), as_bf8(b0l[pb][i]));
            }
            if (epi) {
                #pragma unroll
                for (int i = 0; i < 4; ++i) {
                    int t = tcol[i];
                    float wc2 = WC[512 + t];
                    #pragma unroll
                    for (int j = 0; j < 4; ++j) {
                        int r = lrow + j;
                        int cls = xcl[r][step]; float m = xm[r][step];
                        float ht = tanh_fast(accb[i][j] + m * wc2 + A0t[(6 + cls) * 256 + t]);
                        float hn = (1.f - zv[i][j]) * h0f[i][j] + zv[i][j] * ht;
                        int hx = (r * 256 + t) ^ ((r & 7) << 3);
                        unsigned short hi = f2bf(hn);
                        h0h[hx] = hi; h0l[hx] = f2bf(hn - bf2f(hi));
                    }
                }
            }
        }
        __syncthreads();

        // ====== Phase C: (a) z1,r1 over h0n; (b) wh over h0n; (c) z1,r1 over h1
        {
            f32x4 az1[4], ar1[4];
            #pragma unroll
            for (int i = 0; i < 4; ++i) { az1[i] = fz; ar1[i] = fz; }
            {   // pass a: Wz1,Wr1 over h0n
                bf16x8 fh[2], fl[2];
                uint4 b0h[2][4], b0l[2][4], b1h[2][4], b1l[2][4];
                STG2(0, 0, h0h, h0l, 768, 48, 6);
                #pragma unroll
                for (int c = 0; c < 8; ++c) {
                    if (c & 1) STG2(0, c + 1, h0h, h0l, 768, 48, 6);
                    else       STG2(1, c + 1, h0h, h0l, 768, 48, 6);
                    const int pb = c & 1;
                    #pragma unroll
                    for (int i = 0; i < 4; ++i) {
                        ACC3(az1[i], fh[pb], fl[pb], as_bf8(b0h[pb][i]), as_bf8(b0l[pb][i]));
                        ACC3(ar1[i], fh[pb], fl[pb], as_bf8(b1h[pb][i]), as_bf8(b1l[pb][i]));
                    }
                }
            }
            {   // pass b: Wh1 over h0n
                #pragma unroll
                for (int i = 0; i < 4; ++i) awh[i] = fz;
                bf16x8 fh[2], fl[2];
                uint4 b0h[2][4], b0l[2][4];
                STG1(0, 0, h0h, h0l, 768, 48, 6, 2048);
                #pragma unroll
                for (int c = 0; c < 8; ++c) {
                    if (c & 1) STG1(0, c + 1, h0h, h0l, 768, 48, 6, 2048);
                    else       STG1(1, c + 1, h0h, h0l, 768, 48, 6, 2048);
                    const int pb = c & 1;
                    #pragma unroll
                    for (int i = 0; i < 4; ++i)
                        ACC3(awh[i], fh[pb], fl[pb], as_bf8(b0h[pb][i]), as_bf8(b0l[pb][i]));
                }
            }
            {   // pass c: Uz1,Ur1 over h1
                bf16x8 fh[2], fl[2];
                uint4 b0h[2][4], b0l[2][4], b1h[2][4], b1l[2][4];
                STG2(0, 0, h1h, h1l, 1536, 32, 4);
                #pragma unroll
                for (int c = 0; c < 8; ++c) {
                    if (c & 1) STG2(0, c + 1, h1h, h1l, 1536, 32, 4);
                    else       STG2(1, c + 1, h1h, h1l, 1536, 32, 4);
                    const int pb = c & 1;
                    #pragma unroll
                    for (int i = 0; i < 4; ++i) {
                        ACC3(az1[i], fh[pb], fl[pb], as_bf8(b0h[pb][i]), as_bf8(b0l[pb][i]));
                        ACC3(ar1[i], fh[pb], fl[pb], as_bf8(b1h[pb][i]), as_bf8(b1l[pb][i]));
                    }
                }
            }
            if (epi) {
                #pragma unroll
                for (int i = 0; i < 4; ++i) {
                    int t = tcol[i];
                    #pragma unroll
                    for (int j = 0; j < 4; ++j) {
                        int r = lrow + j;
                        int cls = xcl[r][step];
                        float z1 = sigf(az1[i][j] + B1t[cls * 256 + t]);
                        float r1 = sigf(ar1[i][j] + B1t[(3 + cls) * 256 + t]);
                        int hx = (r * 256 + t) ^ ((r & 7) << 3);
                        float hf = bf2f(h1h[hx]) + bf2f(h1l[hx]);
                        float rh = r1 * hf;
                        unsigned short hi = f2bf(rh);
                        rhh[hx] = hi; rhl[hx] = f2bf(rh - bf2f(hi));
                        z1v[i][j] = z1; h1f[i][j] = hf;
                    }
                }
            }
        }
        __syncthreads();

        // ================= Phase D: (r1.h1) @ Uh1^T =================
        {
            f32x4 accd[4];
            #pragma unroll
            for (int i = 0; i < 4; ++i) accd[i] = fz;
            bf16x8 fh[2], fl[2];
            uint4 b0h[2][4], b0l[2][4];
            STG1(0, 0, rhh, rhl, 2048, 16, 2, 0);
            #pragma unroll
            for (int c = 0; c < 8; ++c) {
                if (c & 1) STG1(0, c + 1, rhh, rhl, 2048, 16, 2, 0);
                else       STG1(1, c + 1, rhh, rhl, 2048, 16, 2, 0);
                const int pb = c & 1;
                #pragma unroll
                for (int i = 0; i < 4; ++i)
                    ACC3(accd[i], fh[pb], fl[pb], as_bf8(b0h[pb][i]), as_bf8(b0l[pb][i]));
            }
            if (epi) {
                #pragma unroll
                for (int i = 0; i < 4; ++i) {
                    int t = tcol[i];
                    #pragma unroll
                    for (int j = 0; j < 4; ++j) {
                        int r = lrow + j;
                        int cls = xcl[r][step];
                        float ht1 = tanh_fast(awh[i][j] + accd[i][j] + B1t[(6 + cls) * 256 + t]);
                        float hn = (1.f - z1v[i][j]) * h1f[i][j] + z1v[i][j] * ht1;
                        int hx = (r * 256 + t) ^ ((r & 7) << 3);
                        unsigned short hi = f2bf(hn);
                        h1h[hx] = hi; h1l[hx] = f2bf(hn - bf2f(hi));
                    }
                }
            }
        }
        __syncthreads();
    }

    // ================= epilogue: out = h1 @ fc_w^T + fc_b =================
    if (tid < BT * PP) {
        int b = tid / PP, p = tid - b * PP;
        float s = fcb[p];
        for (int k = 0; k < H; ++k) {
            int hx = (b * 256 + k) ^ ((b & 7) << 3);
            s += (bf2f(h1h[hx]) + bf2f(h1l[hx])) * fcw[p * H + k];
        }
        out[(size_t)(r0b + b) * PP + p] = s;
    }
}

extern "C" void kernel_launch(void* const* d_in, const int* in_sizes, int n_in,
                              void* d_out, int out_size, void* d_ws, size_t ws_size,
                              hipStream_t stream)
{
    const float* x   = (const float*)d_in[0];
    const float* emb = (const float*)d_in[1];
    const float* Wz0 = (const float*)d_in[2];  const float* Wr0 = (const float*)d_in[3];
    const float* Wh0 = (const float*)d_in[4];
    const float* Uz0 = (const float*)d_in[5];  const float* Ur0 = (const float*)d_in[6];
    const float* Uh0 = (const float*)d_in[7];
    const float* Vw0 = (const float*)d_in[8];  const float* Vb0 = (const float*)d_in[9];
    const float* lz0 = (const float*)d_in[10]; const float* lr0 = (const float*)d_in[11];
    const float* lh0 = (const float*)d_in[12];
    const float* Wz1 = (const float*)d_in[13]; const float* Wr1 = (const float*)d_in[14];
    const float* Wh1 = (const float*)d_in[15];
    const float* Uz1 = (const float*)d_in[16]; const float* Ur1 = (const float*)d_in[17];
    const float* Uh1 = (const float*)d_in[18];
    const float* Vw1 = (const float*)d_in[19]; const float* Vb1 = (const float*)d_in[20];
    const float* lz1 = (const float*)d_in[21]; const float* lr1 = (const float*)d_in[22];
    const float* lh1 = (const float*)d_in[23];
    const float* fcw = (const float*)d_in[24]; const float* fcb = (const float*)d_in[25];

    unsigned short* wsW = (unsigned short*)d_ws;                  // 2304 units * 1KB
    float* cst = (float*)((char*)d_ws + 2359296);                 // 5376 floats (absorbs 1KB over-read)

    hipLaunchKernelGGL(pack_w, dim3(576), dim3(256), 0, stream,
                       Uz0, Ur0, Uh0, Wz1, Wr1, Wh1, Uz1, Ur1, Uh1, wsW);
    hipLaunchKernelGGL(pack_consts, dim3(1), dim3(256), 0, stream,
                       Wz0, Wr0, Wh0, Vw0, Vb0, lz0, lr0, lh0,
                       Wz1, Wr1, Wh1, Vw1, Vb1, lz1, lr1, lh1, emb, cst);
    hipLaunchKernelGGL(trs_scan, dim3(2048 / BT), dim3(256), 0, stream,
                       x, wsW, cst, fcw, fcb, (float*)d_out);
}

// Round 7
// 9621.269 us; speedup vs baseline: 2.8320x; 2.8320x over previous
//
#include <hip/hip_runtime.h>
#include <math.h>

#define H   256
#define TT  128
#define BT  8     // batch rows per block
#define PP  6

typedef float v2f __attribute__((ext_vector_type(2)));

__device__ __forceinline__ float sigf(float x) { return 1.0f / (1.0f + __expf(-x)); }
__device__ __forceinline__ float tanh_fast(float x) {
    float t = __expf(-2.0f * fabsf(x));
    float r = (1.0f - t) / (1.0f + t);
    return copysignf(r, x);
}

// ---------------- pack weights (R2-verified layout) -------------------------
// wbA[(k4*2+g)*256+t] = {Uz0,Ur0}[t][4k4..+3]
// wbH[k4*256+t]       = Uh0[t][4k4..+3]
// wbC[(k4*5+g)*256+t] = g=0..2: {Wz1,Wr1,Wh1}[t][4k4..+3] (ld 264, h0n cols)
//                       g=3,4 : {Uz1,Ur1}[t][4k4..+3]      (ld 256, h1 cols)
// wbD[k4*256+t]       = Uh1[t][4k4..+3]
__global__ void pack_weights(const float* __restrict__ Uz0, const float* __restrict__ Ur0, const float* __restrict__ Uh0,
                             const float* __restrict__ Wz1, const float* __restrict__ Wr1, const float* __restrict__ Wh1,
                             const float* __restrict__ Uz1, const float* __restrict__ Ur1, const float* __restrict__ Uh1,
                             float4* __restrict__ wbA, float4* __restrict__ wbH,
                             float4* __restrict__ wbC, float4* __restrict__ wbD)
{
    int idx = blockIdx.x * 256 + threadIdx.x;   // 0..147455
    if (idx < 32768) {
        int k4 = idx >> 9; int g = (idx >> 8) & 1; int t = idx & 255;
        const float* p = (g ? Ur0 : Uz0) + t * H + k4 * 4;
        wbA[idx] = make_float4(p[0], p[1], p[2], p[3]);
    } else if (idx < 49152) {
        int i = idx - 32768;
        int k4 = i >> 8, t = i & 255;
        const float* p = Uh0 + t * H + k4 * 4;
        wbH[i] = make_float4(p[0], p[1], p[2], p[3]);
    } else if (idx < 131072) {
        int i = idx - 49152;                       // 0..81919
        int k4 = i / 1280; int rem = i - k4 * 1280; int g = rem >> 8; int t = rem & 255;
        const float* p;
        if (g < 3) { const float* W = (g == 0) ? Wz1 : ((g == 1) ? Wr1 : Wh1); p = W + t * 264 + k4 * 4; }
        else       { const float* U = (g == 3) ? Uz1 : Ur1;                    p = U + t * H   + k4 * 4; }
        wbC[i] = make_float4(p[0], p[1], p[2], p[3]);
    } else if (idx < 147456) {
        int i = idx - 131072;
        int k4 = i >> 8, t = i & 255;
        const float* p = Uh1 + t * H + k4 * 4;
        wbD[i] = make_float4(p[0], p[1], p[2], p[3]);
    }
}

// ---- constants, folded (R5-verified): a0f = emb-part + L0*I0 ; b1f same ----
// cst: A0t[3g][3c][256] | B1t[3g][3c][256] | WC[3g][256]   (5376 floats)
__global__ void pack_consts(const float* __restrict__ Wz0, const float* __restrict__ Wr0, const float* __restrict__ Wh0,
                            const float* __restrict__ Vw0, const float* __restrict__ Vb0,
                            const float* __restrict__ lz0, const float* __restrict__ lr0, const float* __restrict__ lh0,
                            const float* __restrict__ Wz1, const float* __restrict__ Wr1, const float* __restrict__ Wh1,
                            const float* __restrict__ Vw1, const float* __restrict__ Vb1,
                            const float* __restrict__ lz1, const float* __restrict__ lr1, const float* __restrict__ lh1,
                            const float* __restrict__ emb, float* __restrict__ cst)
{
    int t = threadIdx.x;
    float* A0t = cst; float* B1t = cst + 2304; float* WC = cst + 4608;
    const float* W0s[3] = {Wz0, Wr0, Wh0};
    const float* W1s[3] = {Wz1, Wr1, Wh1};
    const float* ls0[3] = {lz0, lr0, lh0};
    const float* ls1[3] = {lz1, lr1, lh1};
    for (int g = 0; g < 3; ++g) {
        WC[g * H + t] = W0s[g][t * 9];
        float L0g = 0.05f + 0.45f * sigf(ls0[g][t]);
        float L1g = 0.05f + 0.45f * sigf(ls1[g][t]);
        for (int c = 0; c < 3; ++c) {
            float s0 = 0.f, s1 = 0.f, i0 = Vb0[t], i1 = Vb1[t];
            for (int e = 0; e < 8; ++e) {
                float em = emb[c * 8 + e];
                s0 += W0s[g][t * 9 + 1 + e]     * em;
                s1 += W1s[g][t * 264 + 256 + e] * em;
                i0 += Vw0[t * 8 + e] * em;
                i1 += Vw1[t * 8 + e] * em;
            }
            A0t[(g * 3 + c) * H + t] = s0 + L0g * i0;
            B1t[(g * 3 + c) * H + t] = s1 + L1g * i1;
        }
    }
}

// -------- persistent scan: R2 structure + pk-FMA + depth-4 prefetch ---------
// 256 threads, thread t owns hidden unit t for all 8 rows. All threads/waves
// march the SAME weight address stream (L2-resident, R2-proven).
__global__ __launch_bounds__(256) void trs_scan(
    const float* __restrict__ x,
    const float4* __restrict__ wbA, const float4* __restrict__ wbH,
    const float4* __restrict__ wbC, const float4* __restrict__ wbD,
    const float* __restrict__ cst, const float* __restrict__ fcw, const float* __restrict__ fcb,
    float* __restrict__ out)
{
    __shared__ __align__(16) float h0s[BT][H];
    __shared__ __align__(16) float h1s[BT][H];
    __shared__ __align__(16) float rh0[BT][H];
    __shared__ __align__(16) float rh1[BT][H];
    __shared__ float xm[BT][TT];
    __shared__ unsigned char xcl[BT][TT];

    const int t  = threadIdx.x;
    const int r0 = blockIdx.x * BT;

    const float* A0t = cst; const float* B1t = cst + 2304; const float* WC = cst + 4608;
    float a0f[3][3], b1f[3][3], wc[3];
    #pragma unroll
    for (int g = 0; g < 3; ++g) {
        wc[g] = WC[g * H + t];
        #pragma unroll
        for (int c = 0; c < 3; ++c) {
            a0f[g][c] = A0t[(g * 3 + c) * H + t];
            b1f[g][c] = B1t[(g * 3 + c) * H + t];
        }
    }

    for (int i = t; i < BT * TT; i += 256) {
        int b = i >> 7, tt = i & 127;
        float2 v = *(const float2*)(x + ((size_t)(r0 + b) * TT + tt) * 2);
        xm[b][tt] = v.x;
        int c = (int)v.y; c = c < 0 ? 0 : (c > 2 ? 2 : c);
        xcl[b][tt] = (unsigned char)c;
    }
    #pragma unroll
    for (int b = 0; b < BT; ++b) { h0s[b][t] = 0.f; h1s[b][t] = 0.f; }
    __syncthreads();

    const v2f vz2 = {0.f, 0.f};

    for (int step = 0; step < TT; ++step) {
        float zv[BT], h0v[BT], z1v[BT], h1v[BT], ahWv[BT], mm[BT];
        int cc[BT];
        #pragma unroll
        for (int b = 0; b < BT; ++b) { cc[b] = xcl[b][step]; mm[b] = xm[b][step]; }

        // ===== Phase A: h0 @ {Uz0,Ur0}^T  (depth-4 prefetch ring) =====
        v2f az2[BT], ar2[BT];
        #pragma unroll
        for (int b = 0; b < BT; ++b) { az2[b] = vz2; ar2[b] = vz2; }
        {
            const float4* pA = wbA + t;           // stride 512 f4 per k4
            float4 wz[4], wr[4];
            #pragma unroll
            for (int i = 0; i < 4; ++i) { wz[i] = pA[i * 512]; wr[i] = pA[i * 512 + 256]; }
            for (int kb = 0; kb < 16; ++kb) {
                #pragma unroll
                for (int j = 0; j < 4; ++j) {
                    const int k4 = kb * 4 + j;
                    float4 W1 = wz[j], W2 = wr[j];
                    wz[j] = pA[(k4 + 4) * 512];            // over-read lands in wbH (benign)
                    wr[j] = pA[(k4 + 4) * 512 + 256];
                    v2f w1l = {W1.x, W1.y}, w1h = {W1.z, W1.w};
                    v2f w2l = {W2.x, W2.y}, w2h = {W2.z, W2.w};
                    #pragma unroll
                    for (int b = 0; b < BT; ++b) {
                        float4 a = *(const float4*)&h0s[b][k4 * 4];
                        v2f alo = {a.x, a.y}, ahi = {a.z, a.w};
                        az2[b] += alo * w1l + ahi * w1h;
                        ar2[b] += alo * w2l + ahi * w2h;
                    }
                }
            }
        }
        #pragma unroll
        for (int b = 0; b < BT; ++b) {
            int c = cc[b];
            float z  = sigf(az2[b][0] + az2[b][1] + mm[b] * wc[0] + a0f[0][c]);
            float rg = sigf(ar2[b][0] + ar2[b][1] + mm[b] * wc[1] + a0f[1][c]);
            h0v[b] = h0s[b][t]; zv[b] = z;
            rh0[b][t] = rg * h0v[b];
        }
        __syncthreads();

        // ===== Phase B: (r∘h0) @ Uh0^T  (depth-4) =====
        v2f ab2[BT];
        #pragma unroll
        for (int b = 0; b < BT; ++b) ab2[b] = vz2;
        {
            const float4* pB = wbH + t;           // stride 256
            float4 wh[4];
            #pragma unroll
            for (int i = 0; i < 4; ++i) wh[i] = pB[i * 256];
            for (int kb = 0; kb < 16; ++kb) {
                #pragma unroll
                for (int j = 0; j < 4; ++j) {
                    const int k4 = kb * 4 + j;
                    float4 W1 = wh[j];
                    wh[j] = pB[(k4 + 4) * 256];            // over-read into wbC (benign)
                    v2f w1l = {W1.x, W1.y}, w1h = {W1.z, W1.w};
                    #pragma unroll
                    for (int b = 0; b < BT; ++b) {
                        float4 a = *(const float4*)&rh0[b][k4 * 4];
                        v2f alo = {a.x, a.y}, ahi = {a.z, a.w};
                        ab2[b] += alo * w1l + ahi * w1h;
                    }
                }
            }
        }
        #pragma unroll
        for (int b = 0; b < BT; ++b) {
            int c = cc[b];
            float ht = tanh_fast(ab2[b][0] + ab2[b][1] + mm[b] * wc[2] + a0f[2][c]);
            h0s[b][t] = (1.f - zv[b]) * h0v[b] + zv[b] * ht;
        }
        __syncthreads();

        // ===== Phase C: h0n @ {Wz1,Wr1,Wh1}^T + h1 @ {Uz1,Ur1}^T (depth-2) =====
        v2f cz2[BT], cr2[BT], cw2[BT];
        #pragma unroll
        for (int b = 0; b < BT; ++b) { cz2[b] = vz2; cr2[b] = vz2; cw2[b] = vz2; }
        {
            const float4* pC = wbC + t;           // stride 1280 f4 per k4
            float4 qz[2], qr[2], qw[2], qu[2], qv[2];
            #pragma unroll
            for (int i = 0; i < 2; ++i) {
                qz[i] = pC[i * 1280];        qr[i] = pC[i * 1280 + 256];
                qw[i] = pC[i * 1280 + 512];  qu[i] = pC[i * 1280 + 768];
                qv[i] = pC[i * 1280 + 1024];
            }
            for (int kb = 0; kb < 16; ++kb) {
                #pragma unroll
                for (int j = 0; j < 4; ++j) {
                    const int k4 = kb * 4 + j;
                    const int sl = j & 1;
                    float4 W1 = qz[sl], W2 = qr[sl], W3 = qw[sl], W4 = qu[sl], W5 = qv[sl];
                    int base = (k4 + 2) * 1280;            // over-read into wbD (benign)
                    qz[sl] = pC[base];        qr[sl] = pC[base + 256];
                    qw[sl] = pC[base + 512];  qu[sl] = pC[base + 768];
                    qv[sl] = pC[base + 1024];
                    v2f w1l = {W1.x, W1.y}, w1h = {W1.z, W1.w};
                    v2f w2l = {W2.x, W2.y}, w2h = {W2.z, W2.w};
                    v2f w3l = {W3.x, W3.y}, w3h = {W3.z, W3.w};
                    v2f w4l = {W4.x, W4.y}, w4h = {W4.z, W4.w};
                    v2f w5l = {W5.x, W5.y}, w5h = {W5.z, W5.w};
                    #pragma unroll
                    for (int b = 0; b < BT; ++b) {
                        float4 a = *(const float4*)&h0s[b][k4 * 4];
                        float4 v = *(const float4*)&h1s[b][k4 * 4];
                        v2f alo = {a.x, a.y}, ahi = {a.z, a.w};
                        v2f vlo = {v.x, v.y}, vhi = {v.z, v.w};
                        cz2[b] += alo * w1l + ahi * w1h + vlo * w4l + vhi * w4h;
                        cr2[b] += alo * w2l + ahi * w2h + vlo * w5l + vhi * w5h;
                        cw2[b] += alo * w3l + ahi * w3h;
                    }
                }
            }
        }
        #pragma unroll
        for (int b = 0; b < BT; ++b) {
            int c = cc[b];
            float z1 = sigf(cz2[b][0] + cz2[b][1] + b1f[0][c]);
            float r1 = sigf(cr2[b][0] + cr2[b][1] + b1f[1][c]);
            ahWv[b] = cw2[b][0] + cw2[b][1];
            h1v[b] = h1s[b][t]; z1v[b] = z1;
            rh1[b][t] = r1 * h1v[b];
        }
        __syncthreads();

        // ===== Phase D: (r1∘h1) @ Uh1^T  (depth-4) =====
        v2f ad2[BT];
        #pragma unroll
        for (int b = 0; b < BT; ++b) ad2[b] = vz2;
        {
            const float4* pD = wbD + t;           // stride 256
            float4 wh[4];
            #pragma unroll
            for (int i = 0; i < 4; ++i) wh[i] = pD[i * 256];
            for (int kb = 0; kb < 16; ++kb) {
                #pragma unroll
                for (int j = 0; j < 4; ++j) {
                    const int k4 = kb * 4 + j;
                    float4 W1 = wh[j];
                    wh[j] = pD[(k4 + 4) * 256];            // over-read into cst (benign)
                    v2f w1l = {W1.x, W1.y}, w1h = {W1.z, W1.w};
                    #pragma unroll
                    for (int b = 0; b < BT; ++b) {
                        float4 a = *(const float4*)&rh1[b][k4 * 4];
                        v2f alo = {a.x, a.y}, ahi = {a.z, a.w};
                        ad2[b] += alo * w1l + ahi * w1h;
                    }
                }
            }
        }
        #pragma unroll
        for (int b = 0; b < BT; ++b) {
            int c = cc[b];
            float ht1 = tanh_fast(ahWv[b] + ad2[b][0] + ad2[b][1] + b1f[2][c]);
            h1s[b][t] = (1.f - z1v[b]) * h1v[b] + z1v[b] * ht1;
        }
        __syncthreads();
    }

    // ---- epilogue: out = h1 @ fc_w^T + fc_b
    if (t < BT * PP) {
        int b = t / PP, p = t - b * PP;
        float s = fcb[p];
        for (int h = 0; h < H; ++h) s += h1s[b][h] * fcw[p * H + h];
        out[(size_t)(r0 + b) * PP + p] = s;
    }
}

extern "C" void kernel_launch(void* const* d_in, const int* in_sizes, int n_in,
                              void* d_out, int out_size, void* d_ws, size_t ws_size,
                              hipStream_t stream)
{
    const float* x   = (const float*)d_in[0];
    const float* emb = (const float*)d_in[1];
    const float* Wz0 = (const float*)d_in[2];  const float* Wr0 = (const float*)d_in[3];
    const float* Wh0 = (const float*)d_in[4];
    const float* Uz0 = (const float*)d_in[5];  const float* Ur0 = (const float*)d_in[6];
    const float* Uh0 = (const float*)d_in[7];
    const float* Vw0 = (const float*)d_in[8];  const float* Vb0 = (const float*)d_in[9];
    const float* lz0 = (const float*)d_in[10]; const float* lr0 = (const float*)d_in[11];
    const float* lh0 = (const float*)d_in[12];
    const float* Wz1 = (const float*)d_in[13]; const float* Wr1 = (const float*)d_in[14];
    const float* Wh1 = (const float*)d_in[15];
    const float* Uz1 = (const float*)d_in[16]; const float* Ur1 = (const float*)d_in[17];
    const float* Uh1 = (const float*)d_in[18];
    const float* Vw1 = (const float*)d_in[19]; const float* Vb1 = (const float*)d_in[20];
    const float* lz1 = (const float*)d_in[21]; const float* lr1 = (const float*)d_in[22];
    const float* lh1 = (const float*)d_in[23];
    const float* fcw = (const float*)d_in[24]; const float* fcb = (const float*)d_in[25];

    float*  ws  = (float*)d_ws;
    float4* wbA = (float4*)ws;                         // f4 [0, 32768)
    float4* wbH = (float4*)(ws + 131072);              // f4 [32768, 49152)
    float4* wbC = (float4*)(ws + 196608);              // f4 [49152, 131072)
    float4* wbD = (float4*)(ws + 524288);              // f4 [131072, 147456)
    float*  cst = ws + 589824;                         // 5376 floats (absorbs over-reads)

    hipLaunchKernelGGL(pack_weights, dim3(576), dim3(256), 0, stream,
                       Uz0, Ur0, Uh0, Wz1, Wr1, Wh1, Uz1, Ur1, Uh1, wbA, wbH, wbC, wbD);
    hipLaunchKernelGGL(pack_consts, dim3(1), dim3(256), 0, stream,
                       Wz0, Wr0, Wh0, Vw0, Vb0, lz0, lr0, lh0,
                       Wz1, Wr1, Wh1, Vw1, Vb1, lz1, lr1, lh1, emb, cst);
    hipLaunchKernelGGL(trs_scan, dim3(2048 / BT), dim3(256), 0, stream,
                       x, wbA, wbH, wbC, wbD, cst, fcw, fcb, (float*)d_out);
}